// Round 3
// baseline (2793.659 us; speedup 1.0000x reference)
//
#include <hip/hip_runtime.h>

typedef __attribute__((ext_vector_type(8))) short bf16x8;
typedef __attribute__((ext_vector_type(4))) float f32x4;
typedef unsigned short u16;

__device__ __forceinline__ float bf2f(u16 u) {
  return __uint_as_float(((unsigned)u) << 16);
}
__device__ __forceinline__ u16 f2bf(float x) {
  unsigned u = __float_as_uint(x);
  u += 0x7fffu + ((u >> 16) & 1u);   // RNE
  return (u16)(u >> 16);
}
// flag-aware scalar input load (isbf: bf16, else fp32)
__device__ __forceinline__ float ldin(const void* p, size_t i, bool isbf) {
  return isbf ? bf2f(((const u16*)p)[i]) : ((const float*)p)[i];
}
// flag-aware 8-element load -> bf16 fragment chunk
__device__ __forceinline__ bf16x8 ld8cvt(const void* p, size_t off, bool isbf) {
  if (isbf) return *(const bf16x8*)((const u16*)p + off);
  const float* f = (const float*)p + off;
  float4 a = *(const float4*)f;
  float4 b = *(const float4*)(f + 4);
  bf16x8 r;
  r[0] = (short)f2bf(a.x); r[1] = (short)f2bf(a.y);
  r[2] = (short)f2bf(a.z); r[3] = (short)f2bf(a.w);
  r[4] = (short)f2bf(b.x); r[5] = (short)f2bf(b.y);
  r[6] = (short)f2bf(b.z); r[7] = (short)f2bf(b.w);
  return r;
}

// ---------------------------------------------------------------------------
// Dtype detector: bf16 Gaussian data -> ~100% of shorts have exponent in
// [96,160) (or are exact zero); fp32 data read as bf16 pairs -> ~62%.
// ---------------------------------------------------------------------------
__global__ __launch_bounds__(256) void detect_dtype(const u16* __restrict__ X16,
                                                    int* __restrict__ flag) {
  __shared__ int cnt;
  if (threadIdx.x == 0) cnt = 0;
  __syncthreads();
  int c = 0;
#pragma unroll
  for (int i = 0; i < 8; ++i) {
    u16 v = X16[threadIdx.x * 8 + i];
    int e = (v >> 7) & 0xFF;
    bool sane = (e == 0) ? ((v & 0x7FFF) == 0) : (e >= 96 && e < 160);
    c += sane ? 1 : 0;
  }
  atomicAdd(&cnt, c);
  __syncthreads();
  if (threadIdx.x == 0) flag[0] = (cnt >= 1850) ? 1 : 0;  // 1 = bf16 inputs
}

// ---------------------------------------------------------------------------
// Generic MFMA GEMM: C[M,N] = A[M,K] @ B[N,K]^T, fp32 accumulate.
// A/B may be bf16 or fp32 (amode/bmode: 0=f32, 1=bf16, 2=per dflag).
// 128x128 tile, 256 threads = 4 waves (2x2), wave 64x64 via 4x4 of 16x16x32.
// ---------------------------------------------------------------------------
enum { EPI_F32 = 0, EPI_BF16 = 1, EPI_EG = 2, EPI_SIG = 3, EPI_OUT = 4 };
constexpr int LDT = 40;

__global__ __launch_bounds__(256) void gemm_any(
    const void* __restrict__ A, const void* __restrict__ B,
    float* __restrict__ Cf, u16* __restrict__ Cb,
    int M, int N, int K, int epi,
    const void* __restrict__ dtb, const void* __restrict__ alog,
    int amode, int bmode, const int* __restrict__ dflag) {
  const bool inbf = (dflag[0] != 0);
  const bool abf = (amode == 2) ? inbf : (amode == 1);
  const bool bbf = (bmode == 2) ? inbf : (bmode == 1);

  __shared__ __align__(16) short As[128 * LDT];
  __shared__ __align__(16) short Bs[128 * LDT];
  const int t = threadIdx.x;
  const int n0 = blockIdx.x * 128, m0 = blockIdx.y * 128;
  const int wave = t >> 6, lane = t & 63;
  const int wm = (wave >> 1) << 6, wn = (wave & 1) << 6;
  const int lm = lane & 15, lq = lane >> 4;

  f32x4 acc[4][4];
#pragma unroll
  for (int i = 0; i < 4; ++i)
#pragma unroll
    for (int j = 0; j < 4; ++j) {
      acc[i][j][0] = 0.f; acc[i][j][1] = 0.f;
      acc[i][j][2] = 0.f; acc[i][j][3] = 0.f;
    }

  const int ar = t >> 2;            // 0..63
  const int ac = (t & 3) << 3;      // 0,8,16,24

  for (int kb = 0; kb < K; kb += 32) {
#pragma unroll
    for (int p = 0; p < 2; ++p) {
      int r = ar + (p << 6);
      *(bf16x8*)&As[r * LDT + ac] =
          ld8cvt(A, (size_t)(m0 + r) * K + kb + ac, abf);
      *(bf16x8*)&Bs[r * LDT + ac] =
          ld8cvt(B, (size_t)(n0 + r) * K + kb + ac, bbf);
    }
    __syncthreads();

    bf16x8 af[4], bfr[4];
#pragma unroll
    for (int i = 0; i < 4; ++i)
      af[i] = *(const bf16x8*)&As[(wm + (i << 4) + lm) * LDT + (lq << 3)];
#pragma unroll
    for (int j = 0; j < 4; ++j)
      bfr[j] = *(const bf16x8*)&Bs[(wn + (j << 4) + lm) * LDT + (lq << 3)];
#pragma unroll
    for (int i = 0; i < 4; ++i)
#pragma unroll
      for (int j = 0; j < 4; ++j)
        acc[i][j] = __builtin_amdgcn_mfma_f32_16x16x32_bf16(
            af[i], bfr[j], acc[i][j], 0, 0, 0);
    __syncthreads();
  }

  // C/D layout (verified): col=lane&15, row=(lane>>4)*4+reg.
#pragma unroll
  for (int j = 0; j < 4; ++j) {
    const int col = n0 + wn + (j << 4) + lm;
    float dtv = 0.f, nA = 0.f;
    if (epi == EPI_EG) {
      dtv = ldin(dtb, col, inbf);
      nA = -expf(fminf(ldin(alog, col >> 7, inbf), 20.f));
    }
#pragma unroll
    for (int i = 0; i < 4; ++i) {
#pragma unroll
      for (int r = 0; r < 4; ++r) {
        const int row = m0 + wm + (i << 4) + (lq << 2) + r;
        const size_t off = (size_t)row * N + col;
        float v = acc[i][j][r];
        if (epi == EPI_F32) {
          Cf[off] = v;
        } else if (epi == EPI_BF16) {
          Cb[off] = f2bf(v);
        } else if (epi == EPI_EG) {
          float x = v + dtv;
          float sp = (x > 20.f) ? x : log1pf(expf(x));
          float arg = fmaxf(nA * sp, -87.f);   // clamp; fmaxf scrubs NaN
          Cf[off] = expf(arg);                 // exp(g) in (0,1]
        } else if (epi == EPI_SIG) {
          Cb[off] = f2bf(1.f / (1.f + expf(-v)));
        } else {                               // EPI_OUT: dtype per flag
          if (inbf) Cb[off] = f2bf(v);
          else      Cf[off] = v;
        }
      }
    }
  }
}

// ---------------------------------------------------------------------------
// Depthwise causal conv (K=4) + SiLU + optional L2-norm over dk=128.
// grid (N, H), block 128. mode: 0 none, 1 l2n, 2 l2n * dk^-0.5. out bf16.
// ---------------------------------------------------------------------------
__global__ __launch_bounds__(128) void conv_silu_norm(
    const float* __restrict__ proj, const void* __restrict__ cw,
    u16* __restrict__ out, int mode, const int* __restrict__ dflag) {
  const bool inbf = (dflag[0] != 0);
  const int n = blockIdx.x, h = blockIdx.y, d = threadIdx.x;
  const int col = (h << 7) + d;
  float w0, w1, w2, w3;
  if (inbf) {
    ushort4 wu = *(const ushort4*)((const u16*)cw + col * 4);
    w0 = bf2f(wu.x); w1 = bf2f(wu.y); w2 = bf2f(wu.z); w3 = bf2f(wu.w);
  } else {
    float4 wf = *(const float4*)((const float*)cw + col * 4);
    w0 = wf.x; w1 = wf.y; w2 = wf.z; w3 = wf.w;
  }
  const float* pc = proj + col;
  float acc = 0.f;
  if (n >= 3) acc = fmaf(pc[(size_t)(n - 3) * 4096], w0, acc);
  if (n >= 2) acc = fmaf(pc[(size_t)(n - 2) * 4096], w1, acc);
  if (n >= 1) acc = fmaf(pc[(size_t)(n - 1) * 4096], w2, acc);
  acc = fmaf(pc[(size_t)n * 4096], w3, acc);
  float y = acc / (1.f + expf(-acc));  // silu
  if (mode) {
    float s = y * y;
    s += __shfl_xor(s, 1);  s += __shfl_xor(s, 2);  s += __shfl_xor(s, 4);
    s += __shfl_xor(s, 8);  s += __shfl_xor(s, 16); s += __shfl_xor(s, 32);
    __shared__ float red[2];
    if ((d & 63) == 0) red[d >> 6] = s;
    __syncthreads();
    float sc = rsqrtf(red[0] + red[1] + 1e-6f);
    if (mode == 2) sc *= 0.08838834764831845f;  // dk^-0.5
    y *= sc;
  }
  out[(size_t)n * 4096 + col] = f2bf(y);
}

// ---------------------------------------------------------------------------
// beta = sigmoid(X @ Wb^T). block 64/row; lane t: head t&31, half t>>5.
// ---------------------------------------------------------------------------
__global__ __launch_bounds__(64) void beta_kernel(
    const void* __restrict__ X, const void* __restrict__ Wb,
    float* __restrict__ beta, const int* __restrict__ dflag) {
  const bool inbf = (dflag[0] != 0);
  const int n = blockIdx.x, t = threadIdx.x;
  const int hh = t & 31, half = t >> 5;
  const size_t xo = (size_t)n * 2048 + half * 1024;
  const size_t wo = (size_t)hh * 2048 + half * 1024;
  float acc = 0.f;
  if (inbf) {
    const u16* xr = (const u16*)X + xo;
    const u16* wr = (const u16*)Wb + wo;
    for (int j = 0; j < 1024; j += 4) {
      ushort4 xa = *(const ushort4*)(xr + j);
      ushort4 wa = *(const ushort4*)(wr + j);
      acc = fmaf(bf2f(xa.x), bf2f(wa.x), acc);
      acc = fmaf(bf2f(xa.y), bf2f(wa.y), acc);
      acc = fmaf(bf2f(xa.z), bf2f(wa.z), acc);
      acc = fmaf(bf2f(xa.w), bf2f(wa.w), acc);
    }
  } else {
    const float* xr = (const float*)X + xo;
    const float* wr = (const float*)Wb + wo;
    for (int j = 0; j < 1024; j += 4) {
      float4 xa = *(const float4*)(xr + j);
      float4 wa = *(const float4*)(wr + j);
      acc = fmaf(xa.x, wa.x, acc);
      acc = fmaf(xa.y, wa.y, acc);
      acc = fmaf(xa.z, wa.z, acc);
      acc = fmaf(xa.w, wa.w, acc);
    }
  }
  acc += __shfl_xor(acc, 32);
  if (half == 0) beta[(n << 5) + hh] = 1.f / (1.f + expf(-acc));
}

// ---------------------------------------------------------------------------
// Recurrent delta-rule scan, column-parallel. q/k/v bf16, eg fp32.
// grid 256 = 32 heads x 8 v-blocks(16 cols); block 512; lane owns 4k x 1v.
// ---------------------------------------------------------------------------
__global__ __launch_bounds__(512) void scan_kernel(
    const u16* __restrict__ q, const u16* __restrict__ k,
    const u16* __restrict__ v, const float* __restrict__ eg,
    const float* __restrict__ beta, float* __restrict__ core) {
  const int h = blockIdx.x >> 3, vb = blockIdx.x & 7;
  const int t = threadIdx.x;
  const int kg = t & 31, vloc = t >> 5;
  const int colk = (h << 7) + (kg << 2);
  const int colv = (h << 7) + (vb << 4) + vloc;
  float S0 = 0.f, S1 = 0.f, S2 = 0.f, S3 = 0.f;
  const u16* kp = k + colk;
  const u16* qp = q + colk;
  const float* ep = eg + colk;
  const u16* vp = v + colv;
  float* cp = core + colv;
  for (int n = 0; n < 2048; ++n) {
    const size_t rb = (size_t)n << 12;
    ushort4 ku = *(const ushort4*)(kp + rb);
    ushort4 qu = *(const ushort4*)(qp + rb);
    float4 et = *(const float4*)(ep + rb);
    float vt = bf2f(vp[rb]);
    float bt = beta[(n << 5) + h];
    float k0 = bf2f(ku.x), k1 = bf2f(ku.y), k2 = bf2f(ku.z), k3 = bf2f(ku.w);
    S0 *= et.x; S1 *= et.y; S2 *= et.z; S3 *= et.w;
    float kv = S0 * k0;
    kv = fmaf(S1, k1, kv);
    kv = fmaf(S2, k2, kv);
    kv = fmaf(S3, k3, kv);
    kv += __shfl_xor(kv, 1);
    kv += __shfl_xor(kv, 2);
    kv += __shfl_xor(kv, 4);
    kv += __shfl_xor(kv, 8);
    kv += __shfl_xor(kv, 16);
    float dl = (vt - kv) * bt;
    S0 = fmaf(k0, dl, S0);
    S1 = fmaf(k1, dl, S1);
    S2 = fmaf(k2, dl, S2);
    S3 = fmaf(k3, dl, S3);
    float o = S0 * bf2f(qu.x);
    o = fmaf(S1, bf2f(qu.y), o);
    o = fmaf(S2, bf2f(qu.z), o);
    o = fmaf(S3, bf2f(qu.w), o);
    o += __shfl_xor(o, 1);
    o += __shfl_xor(o, 2);
    o += __shfl_xor(o, 4);
    o += __shfl_xor(o, 8);
    o += __shfl_xor(o, 16);
    if (kg == 0) cp[rb] = o;
  }
}

// ---------------------------------------------------------------------------
// Gated RMSNorm: rms(core) * onorm_w * sigmoid_gate, output bf16.
// ---------------------------------------------------------------------------
__global__ __launch_bounds__(128) void rms_gate(
    const float* __restrict__ core, const u16* __restrict__ sg,
    const void* __restrict__ onw, u16* __restrict__ rb,
    const int* __restrict__ dflag) {
  const bool inbf = (dflag[0] != 0);
  const int n = blockIdx.x, h = blockIdx.y, d = threadIdx.x;
  const int col = (h << 7) + d;
  const size_t off = ((size_t)n << 12) + col;
  float x = core[off];
  float s = x * x;
  s += __shfl_xor(s, 1);  s += __shfl_xor(s, 2);  s += __shfl_xor(s, 4);
  s += __shfl_xor(s, 8);  s += __shfl_xor(s, 16); s += __shfl_xor(s, 32);
  __shared__ float red[2];
  if ((d & 63) == 0) red[d >> 6] = s;
  __syncthreads();
  float tot = red[0] + red[1];
  float r = x * rsqrtf(tot * 0.0078125f + 1e-5f);  // mean over 128
  rb[off] = f2bf(r * ldin(onw, d, inbf) * bf2f(sg[off]));
}

// ---------------------------------------------------------------------------
extern "C" void kernel_launch(void* const* d_in, const int* in_sizes, int n_in,
                              void* d_out, int out_size, void* d_ws, size_t ws_size,
                              hipStream_t stream) {
  const void* X    = d_in[0];
  const void* Wq   = d_in[1];
  const void* Wk   = d_in[2];
  const void* Wv   = d_in[3];
  const void* cq   = d_in[4];
  const void* ck   = d_in[5];
  const void* cv   = d_in[6];
  const void* Wfa  = d_in[7];
  const void* Wfb  = d_in[8];
  const void* dtb  = d_in[9];
  const void* Wb   = d_in[10];
  const void* Alog = d_in[11];
  const void* Wga  = d_in[12];
  const void* Wgb  = d_in[13];
  const void* onw  = d_in[14];
  const void* Wo   = d_in[15];
  char* W = (char*)d_ws;

  const size_t MB = 1024 * 1024;
  const size_t NEED = 114 * MB;
  if (ws_size < NEED) {
    // Diagnostic tripwire: zero (part of) the output and bail. A finite,
    // non-NaN absmax ~= max|ref| in the bench report means ws_size was
    // the blocker, not kernel math.
    hipMemsetAsync(d_out, 0, (size_t)out_size * 2, stream);
    return;
  }

  float* proj  = (float*)(W);                 // 32M fp32; core aliases
  u16*   qb    = (u16*)(W + 32 * MB);         // 16M bf16; rmsb aliases
  u16*   kb    = (u16*)(W + 48 * MB);         // 16M bf16; sgb aliases
  u16*   vb    = (u16*)(W + 64 * MB);         // 16M bf16
  float* eg    = (float*)(W + 80 * MB);       // 32M fp32
  u16*   flowb = (u16*)(W + 112 * MB);        // 512K
  u16*   glowb = (u16*)(W + 112 * MB + 512 * 1024);
  float* betab = (float*)(W + 113 * MB);      // 256K
  int*   dflag = (int*)(W + 113 * MB + 256 * 1024);
  float* core  = proj;
  u16*   sgb   = kb;
  u16*   rmsb  = qb;

  const dim3 gBig(32, 16);    // C [2048,4096]
  const dim3 gLow(1, 16);     // C [2048,128]
  const dim3 gOut(16, 16);    // C [2048,2048]
  const dim3 gNH(2048, 32);

  detect_dtype<<<1, 256, 0, stream>>>((const u16*)X, dflag);

  gemm_any<<<gBig, 256, 0, stream>>>(X, Wq, proj, nullptr, 2048, 4096, 2048,
                                     EPI_F32, nullptr, nullptr, 2, 2, dflag);
  conv_silu_norm<<<gNH, 128, 0, stream>>>(proj, cq, qb, 2, dflag);
  gemm_any<<<gBig, 256, 0, stream>>>(X, Wk, proj, nullptr, 2048, 4096, 2048,
                                     EPI_F32, nullptr, nullptr, 2, 2, dflag);
  conv_silu_norm<<<gNH, 128, 0, stream>>>(proj, ck, kb, 1, dflag);
  gemm_any<<<gBig, 256, 0, stream>>>(X, Wv, proj, nullptr, 2048, 4096, 2048,
                                     EPI_F32, nullptr, nullptr, 2, 2, dflag);
  conv_silu_norm<<<gNH, 128, 0, stream>>>(proj, cv, vb, 0, dflag);

  gemm_any<<<gLow, 256, 0, stream>>>(X, Wfa, nullptr, flowb, 2048, 128, 2048,
                                     EPI_BF16, nullptr, nullptr, 2, 2, dflag);
  gemm_any<<<gLow, 256, 0, stream>>>(X, Wga, nullptr, glowb, 2048, 128, 2048,
                                     EPI_BF16, nullptr, nullptr, 2, 2, dflag);
  beta_kernel<<<2048, 64, 0, stream>>>(X, Wb, betab, dflag);

  gemm_any<<<gBig, 256, 0, stream>>>(flowb, Wfb, eg, nullptr, 2048, 4096, 128,
                                     EPI_EG, dtb, Alog, 1, 2, dflag);

  scan_kernel<<<256, 512, 0, stream>>>(qb, kb, vb, eg, betab, core);

  gemm_any<<<gBig, 256, 0, stream>>>(glowb, Wgb, nullptr, sgb, 2048, 4096, 128,
                                     EPI_SIG, nullptr, nullptr, 1, 2, dflag);
  rms_gate<<<gNH, 128, 0, stream>>>(core, sgb, onw, rmsb, dflag);

  gemm_any<<<gOut, 256, 0, stream>>>(rmsb, Wo, (float*)d_out, (u16*)d_out,
                                     2048, 2048, 4096, EPI_OUT,
                                     nullptr, nullptr, 1, 2, dflag);
}

// Round 4
// 2610.981 us; speedup vs baseline: 1.0700x; 1.0700x over previous
//
#include <hip/hip_runtime.h>

typedef __attribute__((ext_vector_type(8))) short bf16x8;
typedef __attribute__((ext_vector_type(4))) float f32x4;
typedef unsigned short u16;

__device__ __forceinline__ float bf2f(u16 u) {
  return __uint_as_float(((unsigned)u) << 16);
}
__device__ __forceinline__ u16 f2bf(float x) {
  unsigned u = __float_as_uint(x);
  u += 0x7fffu + ((u >> 16) & 1u);   // RNE
  return (u16)(u >> 16);
}
// flag-aware scalar input load (isbf: bf16, else fp32)
__device__ __forceinline__ float ldin(const void* p, size_t i, bool isbf) {
  return isbf ? bf2f(((const u16*)p)[i]) : ((const float*)p)[i];
}
// flag-aware 8-element load -> bf16 fragment chunk
__device__ __forceinline__ bf16x8 ld8cvt(const void* p, size_t off, bool isbf) {
  if (isbf) return *(const bf16x8*)((const u16*)p + off);
  const float* f = (const float*)p + off;
  float4 a = *(const float4*)f;
  float4 b = *(const float4*)(f + 4);
  bf16x8 r;
  r[0] = (short)f2bf(a.x); r[1] = (short)f2bf(a.y);
  r[2] = (short)f2bf(a.z); r[3] = (short)f2bf(a.w);
  r[4] = (short)f2bf(b.x); r[5] = (short)f2bf(b.y);
  r[6] = (short)f2bf(b.z); r[7] = (short)f2bf(b.w);
  return r;
}

// ---------------------------------------------------------------------------
// Dtype detector: bf16 Gaussian data -> ~100% of shorts have exponent in
// [96,160) (or are exact zero); fp32 data read as bf16 pairs -> ~62%.
// ---------------------------------------------------------------------------
__global__ __launch_bounds__(256) void detect_dtype(const u16* __restrict__ X16,
                                                    int* __restrict__ flag) {
  __shared__ int cnt;
  if (threadIdx.x == 0) cnt = 0;
  __syncthreads();
  int c = 0;
#pragma unroll
  for (int i = 0; i < 8; ++i) {
    u16 v = X16[threadIdx.x * 8 + i];
    int e = (v >> 7) & 0xFF;
    bool sane = (e == 0) ? ((v & 0x7FFF) == 0) : (e >= 96 && e < 160);
    c += sane ? 1 : 0;
  }
  atomicAdd(&cnt, c);
  __syncthreads();
  if (threadIdx.x == 0) flag[0] = (cnt >= 1850) ? 1 : 0;  // 1 = bf16 inputs
}

// ---------------------------------------------------------------------------
// Generic MFMA GEMM: C[M,N] = A[M,K] @ B[N,K]^T, fp32 accumulate.
// A/B may be bf16 or fp32 (amode/bmode: 0=f32, 1=bf16, 2=per dflag).
// 128x128 tile, 256 threads = 4 waves (2x2), wave 64x64 via 4x4 of 16x16x32.
// ---------------------------------------------------------------------------
enum { EPI_F32 = 0, EPI_BF16 = 1, EPI_EG = 2, EPI_SIG = 3, EPI_OUT = 4 };
constexpr int LDT = 40;

__global__ __launch_bounds__(256) void gemm_any(
    const void* __restrict__ A, const void* __restrict__ B,
    float* __restrict__ Cf, u16* __restrict__ Cb,
    int M, int N, int K, int epi,
    const void* __restrict__ dtb, const void* __restrict__ alog,
    int amode, int bmode, const int* __restrict__ dflag) {
  const bool inbf = (dflag[0] != 0);
  const bool abf = (amode == 2) ? inbf : (amode == 1);
  const bool bbf = (bmode == 2) ? inbf : (bmode == 1);

  __shared__ __align__(16) short As[128 * LDT];
  __shared__ __align__(16) short Bs[128 * LDT];
  const int t = threadIdx.x;
  const int n0 = blockIdx.x * 128, m0 = blockIdx.y * 128;
  const int wave = t >> 6, lane = t & 63;
  const int wm = (wave >> 1) << 6, wn = (wave & 1) << 6;
  const int lm = lane & 15, lq = lane >> 4;

  f32x4 acc[4][4];
#pragma unroll
  for (int i = 0; i < 4; ++i)
#pragma unroll
    for (int j = 0; j < 4; ++j) {
      acc[i][j][0] = 0.f; acc[i][j][1] = 0.f;
      acc[i][j][2] = 0.f; acc[i][j][3] = 0.f;
    }

  const int ar = t >> 2;            // 0..63
  const int ac = (t & 3) << 3;      // 0,8,16,24

  for (int kb = 0; kb < K; kb += 32) {
#pragma unroll
    for (int p = 0; p < 2; ++p) {
      int r = ar + (p << 6);
      *(bf16x8*)&As[r * LDT + ac] =
          ld8cvt(A, (size_t)(m0 + r) * K + kb + ac, abf);
      *(bf16x8*)&Bs[r * LDT + ac] =
          ld8cvt(B, (size_t)(n0 + r) * K + kb + ac, bbf);
    }
    __syncthreads();

    bf16x8 af[4], bfr[4];
#pragma unroll
    for (int i = 0; i < 4; ++i)
      af[i] = *(const bf16x8*)&As[(wm + (i << 4) + lm) * LDT + (lq << 3)];
#pragma unroll
    for (int j = 0; j < 4; ++j)
      bfr[j] = *(const bf16x8*)&Bs[(wn + (j << 4) + lm) * LDT + (lq << 3)];
#pragma unroll
    for (int i = 0; i < 4; ++i)
#pragma unroll
      for (int j = 0; j < 4; ++j)
        acc[i][j] = __builtin_amdgcn_mfma_f32_16x16x32_bf16(
            af[i], bfr[j], acc[i][j], 0, 0, 0);
    __syncthreads();
  }

  // C/D layout (verified): col=lane&15, row=(lane>>4)*4+reg.
#pragma unroll
  for (int j = 0; j < 4; ++j) {
    const int col = n0 + wn + (j << 4) + lm;
    float dtv = 0.f, nA = 0.f;
    if (epi == EPI_EG) {
      dtv = ldin(dtb, col, inbf);
      nA = -expf(fminf(ldin(alog, col >> 7, inbf), 20.f));
    }
#pragma unroll
    for (int i = 0; i < 4; ++i) {
#pragma unroll
      for (int r = 0; r < 4; ++r) {
        const int row = m0 + wm + (i << 4) + (lq << 2) + r;
        const size_t off = (size_t)row * N + col;
        float v = acc[i][j][r];
        if (epi == EPI_F32) {
          Cf[off] = v;
        } else if (epi == EPI_BF16) {
          Cb[off] = f2bf(v);
        } else if (epi == EPI_EG) {
          float x = v + dtv;
          float sp = (x > 20.f) ? x : log1pf(expf(x));
          float arg = fmaxf(nA * sp, -87.f);   // clamp; fmaxf scrubs NaN
          Cf[off] = expf(arg);                 // exp(g) in (0,1]
        } else if (epi == EPI_SIG) {
          Cb[off] = f2bf(1.f / (1.f + expf(-v)));
        } else {                               // EPI_OUT: dtype per flag
          if (inbf) Cb[off] = f2bf(v);
          else      Cf[off] = v;
        }
      }
    }
  }
}

// ---------------------------------------------------------------------------
// Depthwise causal conv (K=4) + SiLU + optional L2-norm over dk=128.
// grid (N, H), block 128. mode: 0 none, 1 l2n, 2 l2n * dk^-0.5. out bf16.
// ---------------------------------------------------------------------------
__global__ __launch_bounds__(128) void conv_silu_norm(
    const float* __restrict__ proj, const void* __restrict__ cw,
    u16* __restrict__ out, int mode, const int* __restrict__ dflag) {
  const bool inbf = (dflag[0] != 0);
  const int n = blockIdx.x, h = blockIdx.y, d = threadIdx.x;
  const int col = (h << 7) + d;
  float w0, w1, w2, w3;
  if (inbf) {
    ushort4 wu = *(const ushort4*)((const u16*)cw + col * 4);
    w0 = bf2f(wu.x); w1 = bf2f(wu.y); w2 = bf2f(wu.z); w3 = bf2f(wu.w);
  } else {
    float4 wf = *(const float4*)((const float*)cw + col * 4);
    w0 = wf.x; w1 = wf.y; w2 = wf.z; w3 = wf.w;
  }
  const float* pc = proj + col;
  float acc = 0.f;
  if (n >= 3) acc = fmaf(pc[(size_t)(n - 3) * 4096], w0, acc);
  if (n >= 2) acc = fmaf(pc[(size_t)(n - 2) * 4096], w1, acc);
  if (n >= 1) acc = fmaf(pc[(size_t)(n - 1) * 4096], w2, acc);
  acc = fmaf(pc[(size_t)n * 4096], w3, acc);
  float y = acc / (1.f + expf(-acc));  // silu
  if (mode) {
    float s = y * y;
    s += __shfl_xor(s, 1);  s += __shfl_xor(s, 2);  s += __shfl_xor(s, 4);
    s += __shfl_xor(s, 8);  s += __shfl_xor(s, 16); s += __shfl_xor(s, 32);
    __shared__ float red[2];
    if ((d & 63) == 0) red[d >> 6] = s;
    __syncthreads();
    float sc = rsqrtf(red[0] + red[1] + 1e-6f);
    if (mode == 2) sc *= 0.08838834764831845f;  // dk^-0.5
    y *= sc;
  }
  out[(size_t)n * 4096 + col] = f2bf(y);
}

// ---------------------------------------------------------------------------
// beta = sigmoid(X @ Wb^T). block 64/row; lane t: head t&31, half t>>5.
// ---------------------------------------------------------------------------
__global__ __launch_bounds__(64) void beta_kernel(
    const void* __restrict__ X, const void* __restrict__ Wb,
    float* __restrict__ beta, const int* __restrict__ dflag) {
  const bool inbf = (dflag[0] != 0);
  const int n = blockIdx.x, t = threadIdx.x;
  const int hh = t & 31, half = t >> 5;
  const size_t xo = (size_t)n * 2048 + half * 1024;
  const size_t wo = (size_t)hh * 2048 + half * 1024;
  float acc = 0.f;
  if (inbf) {
    const u16* xr = (const u16*)X + xo;
    const u16* wr = (const u16*)Wb + wo;
    for (int j = 0; j < 1024; j += 4) {
      ushort4 xa = *(const ushort4*)(xr + j);
      ushort4 wa = *(const ushort4*)(wr + j);
      acc = fmaf(bf2f(xa.x), bf2f(wa.x), acc);
      acc = fmaf(bf2f(xa.y), bf2f(wa.y), acc);
      acc = fmaf(bf2f(xa.z), bf2f(wa.z), acc);
      acc = fmaf(bf2f(xa.w), bf2f(wa.w), acc);
    }
  } else {
    const float* xr = (const float*)X + xo;
    const float* wr = (const float*)Wb + wo;
    for (int j = 0; j < 1024; j += 4) {
      float4 xa = *(const float4*)(xr + j);
      float4 wa = *(const float4*)(wr + j);
      acc = fmaf(xa.x, wa.x, acc);
      acc = fmaf(xa.y, wa.y, acc);
      acc = fmaf(xa.z, wa.z, acc);
      acc = fmaf(xa.w, wa.w, acc);
    }
  }
  acc += __shfl_xor(acc, 32);
  if (half == 0) beta[(n << 5) + hh] = 1.f / (1.f + expf(-acc));
}

// ---------------------------------------------------------------------------
// Recurrent delta-rule scan, column-parallel. q/k/v bf16, eg fp32.
// grid 256 = 32 heads x 8 v-blocks(16 cols); block 512; lane owns 4k x 1v.
// Software-pipelined: prefetch distance 2, unroll 2 — loads for steps
// n+2/n+3 issue before the dependent compute of steps n/n+1.
// ---------------------------------------------------------------------------
__global__ __launch_bounds__(512) void scan_kernel(
    const u16* __restrict__ q, const u16* __restrict__ k,
    const u16* __restrict__ v, const float* __restrict__ eg,
    const float* __restrict__ beta, float* __restrict__ core) {
  const int h = blockIdx.x >> 3, vb = blockIdx.x & 7;
  const int t = threadIdx.x;
  const int kg = t & 31, vloc = t >> 5;
  const int colk = (h << 7) + (kg << 2);
  const int colv = (h << 7) + (vb << 4) + vloc;
  float S0 = 0.f, S1 = 0.f, S2 = 0.f, S3 = 0.f;
  const u16* kp = k + colk;
  const u16* qp = q + colk;
  const float* ep = eg + colk;
  const u16* vp = v + colv;
  const float* bp = beta + h;
  float* cp = core + colv;

#define KDA_STEP(KU, QU, ET, VT, BT, RB)                                   \
  do {                                                                     \
    float k0 = bf2f(KU.x), k1 = bf2f(KU.y), k2 = bf2f(KU.z),               \
          k3 = bf2f(KU.w);                                                 \
    S0 *= ET.x; S1 *= ET.y; S2 *= ET.z; S3 *= ET.w;                        \
    float kv = S0 * k0;                                                    \
    kv = fmaf(S1, k1, kv);                                                 \
    kv = fmaf(S2, k2, kv);                                                 \
    kv = fmaf(S3, k3, kv);                                                 \
    kv += __shfl_xor(kv, 1);                                               \
    kv += __shfl_xor(kv, 2);                                               \
    kv += __shfl_xor(kv, 4);                                               \
    kv += __shfl_xor(kv, 8);                                               \
    kv += __shfl_xor(kv, 16);                                              \
    float dl = (VT - kv) * BT;                                             \
    S0 = fmaf(k0, dl, S0);                                                 \
    S1 = fmaf(k1, dl, S1);                                                 \
    S2 = fmaf(k2, dl, S2);                                                 \
    S3 = fmaf(k3, dl, S3);                                                 \
    float o = S0 * bf2f(QU.x);                                             \
    o = fmaf(S1, bf2f(QU.y), o);                                           \
    o = fmaf(S2, bf2f(QU.z), o);                                           \
    o = fmaf(S3, bf2f(QU.w), o);                                           \
    o += __shfl_xor(o, 1);                                                 \
    o += __shfl_xor(o, 2);                                                 \
    o += __shfl_xor(o, 4);                                                 \
    o += __shfl_xor(o, 8);                                                 \
    o += __shfl_xor(o, 16);                                                \
    if (kg == 0) cp[RB] = o;                                               \
  } while (0)

  // Pipeline prologue: preload steps 0 and 1.
  ushort4 ku0 = *(const ushort4*)(kp);
  ushort4 qu0 = *(const ushort4*)(qp);
  float4  et0 = *(const float4*)(ep);
  float   vt0 = bf2f(vp[0]);
  float   bt0 = bp[0];
  ushort4 ku1 = *(const ushort4*)(kp + 4096);
  ushort4 qu1 = *(const ushort4*)(qp + 4096);
  float4  et1 = *(const float4*)(ep + 4096);
  float   vt1 = bf2f(vp[4096]);
  float   bt1 = bp[32];

  for (int n = 0; n < 2048; n += 2) {
    const int n2 = (n + 2 < 2048) ? n + 2 : 2046;  // clamped; dead when OOB
    const int n3 = (n + 3 < 2048) ? n + 3 : 2046;
    const size_t r2 = (size_t)n2 << 12;
    const size_t r3 = (size_t)n3 << 12;
    ushort4 ku2 = *(const ushort4*)(kp + r2);
    ushort4 qu2 = *(const ushort4*)(qp + r2);
    float4  et2 = *(const float4*)(ep + r2);
    float   vt2 = bf2f(vp[r2]);
    float   bt2 = bp[(size_t)n2 << 5];
    ushort4 ku3 = *(const ushort4*)(kp + r3);
    ushort4 qu3 = *(const ushort4*)(qp + r3);
    float4  et3 = *(const float4*)(ep + r3);
    float   vt3 = bf2f(vp[r3]);
    float   bt3 = bp[(size_t)n3 << 5];

    KDA_STEP(ku0, qu0, et0, vt0, bt0, (size_t)n << 12);
    KDA_STEP(ku1, qu1, et1, vt1, bt1, (size_t)(n + 1) << 12);

    ku0 = ku2; qu0 = qu2; et0 = et2; vt0 = vt2; bt0 = bt2;
    ku1 = ku3; qu1 = qu3; et1 = et3; vt1 = vt3; bt1 = bt3;
  }
#undef KDA_STEP
}

// ---------------------------------------------------------------------------
// Gated RMSNorm: rms(core) * onorm_w * sigmoid_gate, output bf16.
// ---------------------------------------------------------------------------
__global__ __launch_bounds__(128) void rms_gate(
    const float* __restrict__ core, const u16* __restrict__ sg,
    const void* __restrict__ onw, u16* __restrict__ rb,
    const int* __restrict__ dflag) {
  const bool inbf = (dflag[0] != 0);
  const int n = blockIdx.x, h = blockIdx.y, d = threadIdx.x;
  const int col = (h << 7) + d;
  const size_t off = ((size_t)n << 12) + col;
  float x = core[off];
  float s = x * x;
  s += __shfl_xor(s, 1);  s += __shfl_xor(s, 2);  s += __shfl_xor(s, 4);
  s += __shfl_xor(s, 8);  s += __shfl_xor(s, 16); s += __shfl_xor(s, 32);
  __shared__ float red[2];
  if ((d & 63) == 0) red[d >> 6] = s;
  __syncthreads();
  float tot = red[0] + red[1];
  float r = x * rsqrtf(tot * 0.0078125f + 1e-5f);  // mean over 128
  rb[off] = f2bf(r * ldin(onw, d, inbf) * bf2f(sg[off]));
}

// ---------------------------------------------------------------------------
extern "C" void kernel_launch(void* const* d_in, const int* in_sizes, int n_in,
                              void* d_out, int out_size, void* d_ws, size_t ws_size,
                              hipStream_t stream) {
  const void* X    = d_in[0];
  const void* Wq   = d_in[1];
  const void* Wk   = d_in[2];
  const void* Wv   = d_in[3];
  const void* cq   = d_in[4];
  const void* ck   = d_in[5];
  const void* cv   = d_in[6];
  const void* Wfa  = d_in[7];
  const void* Wfb  = d_in[8];
  const void* dtb  = d_in[9];
  const void* Wb   = d_in[10];
  const void* Alog = d_in[11];
  const void* Wga  = d_in[12];
  const void* Wgb  = d_in[13];
  const void* onw  = d_in[14];
  const void* Wo   = d_in[15];
  char* W = (char*)d_ws;

  const size_t MB = 1024 * 1024;
  const size_t NEED = 114 * MB;
  if (ws_size < NEED) {
    hipMemsetAsync(d_out, 0, (size_t)out_size * 2, stream);
    return;
  }

  float* proj  = (float*)(W);                 // 32M fp32; core aliases
  u16*   qb    = (u16*)(W + 32 * MB);         // 16M bf16; rmsb aliases
  u16*   kb    = (u16*)(W + 48 * MB);         // 16M bf16; sgb aliases
  u16*   vb    = (u16*)(W + 64 * MB);         // 16M bf16
  float* eg    = (float*)(W + 80 * MB);       // 32M fp32
  u16*   flowb = (u16*)(W + 112 * MB);        // 512K
  u16*   glowb = (u16*)(W + 112 * MB + 512 * 1024);
  float* betab = (float*)(W + 113 * MB);      // 256K
  int*   dflag = (int*)(W + 113 * MB + 256 * 1024);
  float* core  = proj;
  u16*   sgb   = kb;
  u16*   rmsb  = qb;

  const dim3 gBig(32, 16);    // C [2048,4096]
  const dim3 gLow(1, 16);     // C [2048,128]
  const dim3 gOut(16, 16);    // C [2048,2048]
  const dim3 gNH(2048, 32);

  detect_dtype<<<1, 256, 0, stream>>>((const u16*)X, dflag);

  gemm_any<<<gBig, 256, 0, stream>>>(X, Wq, proj, nullptr, 2048, 4096, 2048,
                                     EPI_F32, nullptr, nullptr, 2, 2, dflag);
  conv_silu_norm<<<gNH, 128, 0, stream>>>(proj, cq, qb, 2, dflag);
  gemm_any<<<gBig, 256, 0, stream>>>(X, Wk, proj, nullptr, 2048, 4096, 2048,
                                     EPI_F32, nullptr, nullptr, 2, 2, dflag);
  conv_silu_norm<<<gNH, 128, 0, stream>>>(proj, ck, kb, 1, dflag);
  gemm_any<<<gBig, 256, 0, stream>>>(X, Wv, proj, nullptr, 2048, 4096, 2048,
                                     EPI_F32, nullptr, nullptr, 2, 2, dflag);
  conv_silu_norm<<<gNH, 128, 0, stream>>>(proj, cv, vb, 0, dflag);

  gemm_any<<<gLow, 256, 0, stream>>>(X, Wfa, nullptr, flowb, 2048, 128, 2048,
                                     EPI_BF16, nullptr, nullptr, 2, 2, dflag);
  gemm_any<<<gLow, 256, 0, stream>>>(X, Wga, nullptr, glowb, 2048, 128, 2048,
                                     EPI_BF16, nullptr, nullptr, 2, 2, dflag);
  beta_kernel<<<2048, 64, 0, stream>>>(X, Wb, betab, dflag);

  gemm_any<<<gBig, 256, 0, stream>>>(flowb, Wfb, eg, nullptr, 2048, 4096, 128,
                                     EPI_EG, dtb, Alog, 1, 2, dflag);

  scan_kernel<<<256, 512, 0, stream>>>(qb, kb, vb, eg, betab, core);

  gemm_any<<<gBig, 256, 0, stream>>>(glowb, Wgb, nullptr, sgb, 2048, 4096, 128,
                                     EPI_SIG, nullptr, nullptr, 1, 2, dflag);
  rms_gate<<<gNH, 128, 0, stream>>>(core, sgb, onw, rmsb, dflag);

  gemm_any<<<gOut, 256, 0, stream>>>(rmsb, Wo, (float*)d_out, (u16*)d_out,
                                     2048, 2048, 4096, EPI_OUT,
                                     nullptr, nullptr, 1, 2, dflag);
}

// Round 5
// 2127.406 us; speedup vs baseline: 1.3132x; 1.2273x over previous
//
#include <hip/hip_runtime.h>

typedef __attribute__((ext_vector_type(8))) short bf16x8;
typedef __attribute__((ext_vector_type(4))) float f32x4;
typedef unsigned short u16;

__device__ __forceinline__ float bf2f(u16 u) {
  return __uint_as_float(((unsigned)u) << 16);
}
__device__ __forceinline__ u16 f2bf(float x) {
  unsigned u = __float_as_uint(x);
  u += 0x7fffu + ((u >> 16) & 1u);   // RNE
  return (u16)(u >> 16);
}
// flag-aware scalar input load (isbf: bf16, else fp32)
__device__ __forceinline__ float ldin(const void* p, size_t i, bool isbf) {
  return isbf ? bf2f(((const u16*)p)[i]) : ((const float*)p)[i];
}
// flag-aware 8-element load -> bf16 fragment chunk
__device__ __forceinline__ bf16x8 ld8cvt(const void* p, size_t off, bool isbf) {
  if (isbf) return *(const bf16x8*)((const u16*)p + off);
  const float* f = (const float*)p + off;
  float4 a = *(const float4*)f;
  float4 b = *(const float4*)(f + 4);
  bf16x8 r;
  r[0] = (short)f2bf(a.x); r[1] = (short)f2bf(a.y);
  r[2] = (short)f2bf(a.z); r[3] = (short)f2bf(a.w);
  r[4] = (short)f2bf(b.x); r[5] = (short)f2bf(b.y);
  r[6] = (short)f2bf(b.z); r[7] = (short)f2bf(b.w);
  return r;
}

// ---------------------------------------------------------------------------
// Dtype detector: bf16 Gaussian data -> ~100% of shorts have exponent in
// [96,160) (or are exact zero); fp32 data read as bf16 pairs -> ~62%.
// ---------------------------------------------------------------------------
__global__ __launch_bounds__(256) void detect_dtype(const u16* __restrict__ X16,
                                                    int* __restrict__ flag) {
  __shared__ int cnt;
  if (threadIdx.x == 0) cnt = 0;
  __syncthreads();
  int c = 0;
#pragma unroll
  for (int i = 0; i < 8; ++i) {
    u16 v = X16[threadIdx.x * 8 + i];
    int e = (v >> 7) & 0xFF;
    bool sane = (e == 0) ? ((v & 0x7FFF) == 0) : (e >= 96 && e < 160);
    c += sane ? 1 : 0;
  }
  atomicAdd(&cnt, c);
  __syncthreads();
  if (threadIdx.x == 0) flag[0] = (cnt >= 1850) ? 1 : 0;  // 1 = bf16 inputs
}

// ---------------------------------------------------------------------------
// Generic MFMA GEMM: C[M,N] = A[M,K] @ B[N,K]^T, fp32 accumulate.
// A/B may be bf16 or fp32 (amode/bmode: 0=f32, 1=bf16, 2=per dflag).
// 128x128 tile, 256 threads = 4 waves (2x2), wave 64x64 via 4x4 of 16x16x32.
// ---------------------------------------------------------------------------
enum { EPI_F32 = 0, EPI_BF16 = 1, EPI_EG = 2, EPI_SIG = 3, EPI_OUT = 4 };
constexpr int LDT = 40;

__global__ __launch_bounds__(256) void gemm_any(
    const void* __restrict__ A, const void* __restrict__ B,
    float* __restrict__ Cf, u16* __restrict__ Cb,
    int M, int N, int K, int epi,
    const void* __restrict__ dtb, const void* __restrict__ alog,
    int amode, int bmode, const int* __restrict__ dflag) {
  const bool inbf = (dflag[0] != 0);
  const bool abf = (amode == 2) ? inbf : (amode == 1);
  const bool bbf = (bmode == 2) ? inbf : (bmode == 1);

  __shared__ __align__(16) short As[128 * LDT];
  __shared__ __align__(16) short Bs[128 * LDT];
  const int t = threadIdx.x;
  const int n0 = blockIdx.x * 128, m0 = blockIdx.y * 128;
  const int wave = t >> 6, lane = t & 63;
  const int wm = (wave >> 1) << 6, wn = (wave & 1) << 6;
  const int lm = lane & 15, lq = lane >> 4;

  f32x4 acc[4][4];
#pragma unroll
  for (int i = 0; i < 4; ++i)
#pragma unroll
    for (int j = 0; j < 4; ++j) {
      acc[i][j][0] = 0.f; acc[i][j][1] = 0.f;
      acc[i][j][2] = 0.f; acc[i][j][3] = 0.f;
    }

  const int ar = t >> 2;            // 0..63
  const int ac = (t & 3) << 3;      // 0,8,16,24

  for (int kb = 0; kb < K; kb += 32) {
#pragma unroll
    for (int p = 0; p < 2; ++p) {
      int r = ar + (p << 6);
      *(bf16x8*)&As[r * LDT + ac] =
          ld8cvt(A, (size_t)(m0 + r) * K + kb + ac, abf);
      *(bf16x8*)&Bs[r * LDT + ac] =
          ld8cvt(B, (size_t)(n0 + r) * K + kb + ac, bbf);
    }
    __syncthreads();

    bf16x8 af[4], bfr[4];
#pragma unroll
    for (int i = 0; i < 4; ++i)
      af[i] = *(const bf16x8*)&As[(wm + (i << 4) + lm) * LDT + (lq << 3)];
#pragma unroll
    for (int j = 0; j < 4; ++j)
      bfr[j] = *(const bf16x8*)&Bs[(wn + (j << 4) + lm) * LDT + (lq << 3)];
#pragma unroll
    for (int i = 0; i < 4; ++i)
#pragma unroll
      for (int j = 0; j < 4; ++j)
        acc[i][j] = __builtin_amdgcn_mfma_f32_16x16x32_bf16(
            af[i], bfr[j], acc[i][j], 0, 0, 0);
    __syncthreads();
  }

  // C/D layout (verified): col=lane&15, row=(lane>>4)*4+reg.
#pragma unroll
  for (int j = 0; j < 4; ++j) {
    const int col = n0 + wn + (j << 4) + lm;
    float dtv = 0.f, nA = 0.f;
    if (epi == EPI_EG) {
      dtv = ldin(dtb, col, inbf);
      nA = -expf(fminf(ldin(alog, col >> 7, inbf), 20.f));
    }
#pragma unroll
    for (int i = 0; i < 4; ++i) {
#pragma unroll
      for (int r = 0; r < 4; ++r) {
        const int row = m0 + wm + (i << 4) + (lq << 2) + r;
        const size_t off = (size_t)row * N + col;
        float v = acc[i][j][r];
        if (epi == EPI_F32) {
          Cf[off] = v;
        } else if (epi == EPI_BF16) {
          Cb[off] = f2bf(v);
        } else if (epi == EPI_EG) {
          float x = v + dtv;
          float sp = (x > 20.f) ? x : log1pf(expf(x));
          float arg = fmaxf(nA * sp, -87.f);   // clamp; fmaxf scrubs NaN
          Cf[off] = expf(arg);                 // exp(g) in (0,1]
        } else if (epi == EPI_SIG) {
          Cb[off] = f2bf(1.f / (1.f + expf(-v)));
        } else {                               // EPI_OUT: dtype per flag
          if (inbf) Cb[off] = f2bf(v);
          else      Cf[off] = v;
        }
      }
    }
  }
}

// ---------------------------------------------------------------------------
// Depthwise causal conv (K=4) + SiLU + optional L2-norm over dk=128.
// grid (N, H), block 128. mode: 0 none, 1 l2n, 2 l2n * dk^-0.5. out bf16.
// ---------------------------------------------------------------------------
__global__ __launch_bounds__(128) void conv_silu_norm(
    const float* __restrict__ proj, const void* __restrict__ cw,
    u16* __restrict__ out, int mode, const int* __restrict__ dflag) {
  const bool inbf = (dflag[0] != 0);
  const int n = blockIdx.x, h = blockIdx.y, d = threadIdx.x;
  const int col = (h << 7) + d;
  float w0, w1, w2, w3;
  if (inbf) {
    ushort4 wu = *(const ushort4*)((const u16*)cw + col * 4);
    w0 = bf2f(wu.x); w1 = bf2f(wu.y); w2 = bf2f(wu.z); w3 = bf2f(wu.w);
  } else {
    float4 wf = *(const float4*)((const float*)cw + col * 4);
    w0 = wf.x; w1 = wf.y; w2 = wf.z; w3 = wf.w;
  }
  const float* pc = proj + col;
  float acc = 0.f;
  if (n >= 3) acc = fmaf(pc[(size_t)(n - 3) * 4096], w0, acc);
  if (n >= 2) acc = fmaf(pc[(size_t)(n - 2) * 4096], w1, acc);
  if (n >= 1) acc = fmaf(pc[(size_t)(n - 1) * 4096], w2, acc);
  acc = fmaf(pc[(size_t)n * 4096], w3, acc);
  float y = acc / (1.f + expf(-acc));  // silu
  if (mode) {
    float s = y * y;
    s += __shfl_xor(s, 1);  s += __shfl_xor(s, 2);  s += __shfl_xor(s, 4);
    s += __shfl_xor(s, 8);  s += __shfl_xor(s, 16); s += __shfl_xor(s, 32);
    __shared__ float red[2];
    if ((d & 63) == 0) red[d >> 6] = s;
    __syncthreads();
    float sc = rsqrtf(red[0] + red[1] + 1e-6f);
    if (mode == 2) sc *= 0.08838834764831845f;  // dk^-0.5
    y *= sc;
  }
  out[(size_t)n * 4096 + col] = f2bf(y);
}

// ---------------------------------------------------------------------------
// beta = sigmoid(X @ Wb^T). block 64/row; lane t: head t&31, half t>>5.
// ---------------------------------------------------------------------------
__global__ __launch_bounds__(64) void beta_kernel(
    const void* __restrict__ X, const void* __restrict__ Wb,
    float* __restrict__ beta, const int* __restrict__ dflag) {
  const bool inbf = (dflag[0] != 0);
  const int n = blockIdx.x, t = threadIdx.x;
  const int hh = t & 31, half = t >> 5;
  const size_t xo = (size_t)n * 2048 + half * 1024;
  const size_t wo = (size_t)hh * 2048 + half * 1024;
  float acc = 0.f;
  if (inbf) {
    const u16* xr = (const u16*)X + xo;
    const u16* wr = (const u16*)Wb + wo;
    for (int j = 0; j < 1024; j += 4) {
      ushort4 xa = *(const ushort4*)(xr + j);
      ushort4 wa = *(const ushort4*)(wr + j);
      acc = fmaf(bf2f(xa.x), bf2f(wa.x), acc);
      acc = fmaf(bf2f(xa.y), bf2f(wa.y), acc);
      acc = fmaf(bf2f(xa.z), bf2f(wa.z), acc);
      acc = fmaf(bf2f(xa.w), bf2f(wa.w), acc);
    }
  } else {
    const float* xr = (const float*)X + xo;
    const float* wr = (const float*)Wb + wo;
    for (int j = 0; j < 1024; j += 4) {
      float4 xa = *(const float4*)(xr + j);
      float4 wa = *(const float4*)(wr + j);
      acc = fmaf(xa.x, wa.x, acc);
      acc = fmaf(xa.y, wa.y, acc);
      acc = fmaf(xa.z, wa.z, acc);
      acc = fmaf(xa.w, wa.w, acc);
    }
  }
  acc += __shfl_xor(acc, 32);
  if (half == 0) beta[(n << 5) + hh] = 1.f / (1.f + expf(-acc));
}

// ---------------------------------------------------------------------------
// DPP 16-lane row reduction: 4 dependent VALU adds, no LDS.
// Masks {xor1(quad_perm), xor2(quad_perm), ror4, ror8} — valid because
// partial sums are quad-uniform after the first two levels.
// ---------------------------------------------------------------------------
template <int CTRL>
__device__ __forceinline__ float dpp_add(float x) {
  int t = __builtin_amdgcn_update_dpp(0, __float_as_int(x), CTRL, 0xF, 0xF,
                                      true);
  return x + __int_as_float(t);
}
__device__ __forceinline__ float row16_sum(float x) {
  x = dpp_add<0xB1>(x);   // quad_perm [1,0,3,2] = xor1
  x = dpp_add<0x4E>(x);   // quad_perm [2,3,0,1] = xor2
  x = dpp_add<0x124>(x);  // row_ror:4
  x = dpp_add<0x128>(x);  // row_ror:8
  return x;
}
__device__ __forceinline__ void unp8(uint4 w, float* f) {
  f[0] = __uint_as_float(w.x << 16); f[1] = __uint_as_float(w.x & 0xffff0000u);
  f[2] = __uint_as_float(w.y << 16); f[3] = __uint_as_float(w.y & 0xffff0000u);
  f[4] = __uint_as_float(w.z << 16); f[5] = __uint_as_float(w.z & 0xffff0000u);
  f[6] = __uint_as_float(w.w << 16); f[7] = __uint_as_float(w.w & 0xffff0000u);
}

// ---------------------------------------------------------------------------
// Recurrent delta-rule scan, column-parallel. q/k/v bf16, eg fp32.
// grid 256 = 32 heads x 8 v-blocks(16 cols); block 256 = 16 klanes x 16 v.
// Each lane owns 8 k-channels x 1 v; k-reduction = 16-lane DPP row sum
// (zero DS ops on the recurrence path). Prefetch distance 2, unroll 2.
// ---------------------------------------------------------------------------
__device__ __forceinline__ void kda_step(float S[8], uint4 kw, uint4 qw,
                                         float4 ea, float4 eb, float vt,
                                         float bt, bool lead, float* cdst) {
  float kf[8], qf[8];
  unp8(kw, kf);
  unp8(qw, qf);
  S[0] *= ea.x; S[1] *= ea.y; S[2] *= ea.z; S[3] *= ea.w;
  S[4] *= eb.x; S[5] *= eb.y; S[6] *= eb.z; S[7] *= eb.w;
  float m0 = fmaf(S[1], kf[1], S[0] * kf[0]);
  float m1 = fmaf(S[3], kf[3], S[2] * kf[2]);
  float m2 = fmaf(S[5], kf[5], S[4] * kf[4]);
  float m3 = fmaf(S[7], kf[7], S[6] * kf[6]);
  float kv = row16_sum((m0 + m1) + (m2 + m3));
  float dl = (vt - kv) * bt;
  S[0] = fmaf(kf[0], dl, S[0]);
  S[1] = fmaf(kf[1], dl, S[1]);
  S[2] = fmaf(kf[2], dl, S[2]);
  S[3] = fmaf(kf[3], dl, S[3]);
  S[4] = fmaf(kf[4], dl, S[4]);
  S[5] = fmaf(kf[5], dl, S[5]);
  S[6] = fmaf(kf[6], dl, S[6]);
  S[7] = fmaf(kf[7], dl, S[7]);
  float o0 = fmaf(S[1], qf[1], S[0] * qf[0]);
  float o1 = fmaf(S[3], qf[3], S[2] * qf[2]);
  float o2 = fmaf(S[5], qf[5], S[4] * qf[4]);
  float o3 = fmaf(S[7], qf[7], S[6] * qf[6]);
  float o = row16_sum((o0 + o1) + (o2 + o3));
  if (lead) *cdst = o;
}

__global__ __launch_bounds__(256) void scan_kernel(
    const u16* __restrict__ q, const u16* __restrict__ k,
    const u16* __restrict__ v, const float* __restrict__ eg,
    const float* __restrict__ beta, float* __restrict__ core) {
  const int h = blockIdx.x >> 3, vb = blockIdx.x & 7;
  const int t = threadIdx.x;
  const int kl = t & 15;           // k-lane: owns channels [kl*8, kl*8+8)
  const int vloc = t >> 4;         // 0..15
  const int colk = (h << 7) + (kl << 3);
  const int colv = (h << 7) + (vb << 4) + vloc;
  const bool lead = (kl == 0);
  float S[8] = {0.f, 0.f, 0.f, 0.f, 0.f, 0.f, 0.f, 0.f};
  const u16* kp = k + colk;
  const u16* qp = q + colk;
  const float* ep = eg + colk;
  const u16* vp = v + colv;
  const float* bp = beta + h;
  float* cp = core + colv;

  // Prologue: preload steps 0 and 1.
  uint4  kw0 = *(const uint4*)(kp);
  uint4  qw0 = *(const uint4*)(qp);
  float4 ea0 = *(const float4*)(ep);
  float4 eb0 = *(const float4*)(ep + 4);
  float  vt0 = bf2f(vp[0]);
  float  bt0 = bp[0];
  uint4  kw1 = *(const uint4*)(kp + 4096);
  uint4  qw1 = *(const uint4*)(qp + 4096);
  float4 ea1 = *(const float4*)(ep + 4096);
  float4 eb1 = *(const float4*)(ep + 4100);
  float  vt1 = bf2f(vp[4096]);
  float  bt1 = bp[32];

  for (int n = 0; n < 2048; n += 2) {
    const int n2 = (n + 2 < 2048) ? n + 2 : 2046;  // clamped; dead when OOB
    const int n3 = (n + 3 < 2048) ? n + 3 : 2046;
    const size_t r2 = (size_t)n2 << 12;
    const size_t r3 = (size_t)n3 << 12;
    uint4  kw2 = *(const uint4*)(kp + r2);
    uint4  qw2 = *(const uint4*)(qp + r2);
    float4 ea2 = *(const float4*)(ep + r2);
    float4 eb2 = *(const float4*)(ep + r2 + 4);
    float  vt2 = bf2f(vp[r2]);
    float  bt2 = bp[(size_t)n2 << 5];
    uint4  kw3 = *(const uint4*)(kp + r3);
    uint4  qw3 = *(const uint4*)(qp + r3);
    float4 ea3 = *(const float4*)(ep + r3);
    float4 eb3 = *(const float4*)(ep + r3 + 4);
    float  vt3 = bf2f(vp[r3]);
    float  bt3 = bp[(size_t)n3 << 5];

    kda_step(S, kw0, qw0, ea0, eb0, vt0, bt0, lead, cp + ((size_t)n << 12));
    kda_step(S, kw1, qw1, ea1, eb1, vt1, bt1, lead,
             cp + ((size_t)(n + 1) << 12));

    kw0 = kw2; qw0 = qw2; ea0 = ea2; eb0 = eb2; vt0 = vt2; bt0 = bt2;
    kw1 = kw3; qw1 = qw3; ea1 = ea3; eb1 = eb3; vt1 = vt3; bt1 = bt3;
  }
}

// ---------------------------------------------------------------------------
// Gated RMSNorm: rms(core) * onorm_w * sigmoid_gate, output bf16.
// ---------------------------------------------------------------------------
__global__ __launch_bounds__(128) void rms_gate(
    const float* __restrict__ core, const u16* __restrict__ sg,
    const void* __restrict__ onw, u16* __restrict__ rb,
    const int* __restrict__ dflag) {
  const bool inbf = (dflag[0] != 0);
  const int n = blockIdx.x, h = blockIdx.y, d = threadIdx.x;
  const int col = (h << 7) + d;
  const size_t off = ((size_t)n << 12) + col;
  float x = core[off];
  float s = x * x;
  s += __shfl_xor(s, 1);  s += __shfl_xor(s, 2);  s += __shfl_xor(s, 4);
  s += __shfl_xor(s, 8);  s += __shfl_xor(s, 16); s += __shfl_xor(s, 32);
  __shared__ float red[2];
  if ((d & 63) == 0) red[d >> 6] = s;
  __syncthreads();
  float tot = red[0] + red[1];
  float r = x * rsqrtf(tot * 0.0078125f + 1e-5f);  // mean over 128
  rb[off] = f2bf(r * ldin(onw, d, inbf) * bf2f(sg[off]));
}

// ---------------------------------------------------------------------------
extern "C" void kernel_launch(void* const* d_in, const int* in_sizes, int n_in,
                              void* d_out, int out_size, void* d_ws, size_t ws_size,
                              hipStream_t stream) {
  const void* X    = d_in[0];
  const void* Wq   = d_in[1];
  const void* Wk   = d_in[2];
  const void* Wv   = d_in[3];
  const void* cq   = d_in[4];
  const void* ck   = d_in[5];
  const void* cv   = d_in[6];
  const void* Wfa  = d_in[7];
  const void* Wfb  = d_in[8];
  const void* dtb  = d_in[9];
  const void* Wb   = d_in[10];
  const void* Alog = d_in[11];
  const void* Wga  = d_in[12];
  const void* Wgb  = d_in[13];
  const void* onw  = d_in[14];
  const void* Wo   = d_in[15];
  char* W = (char*)d_ws;

  const size_t MB = 1024 * 1024;
  const size_t NEED = 114 * MB;
  if (ws_size < NEED) {
    hipMemsetAsync(d_out, 0, (size_t)out_size * 2, stream);
    return;
  }

  float* proj  = (float*)(W);                 // 32M fp32; core aliases
  u16*   qb    = (u16*)(W + 32 * MB);         // 16M bf16; rmsb aliases
  u16*   kb    = (u16*)(W + 48 * MB);         // 16M bf16; sgb aliases
  u16*   vb    = (u16*)(W + 64 * MB);         // 16M bf16
  float* eg    = (float*)(W + 80 * MB);       // 32M fp32
  u16*   flowb = (u16*)(W + 112 * MB);        // 512K
  u16*   glowb = (u16*)(W + 112 * MB + 512 * 1024);
  float* betab = (float*)(W + 113 * MB);      // 256K
  int*   dflag = (int*)(W + 113 * MB + 256 * 1024);
  float* core  = proj;
  u16*   sgb   = kb;
  u16*   rmsb  = qb;

  const dim3 gBig(32, 16);    // C [2048,4096]
  const dim3 gLow(1, 16);     // C [2048,128]
  const dim3 gOut(16, 16);    // C [2048,2048]
  const dim3 gNH(2048, 32);

  detect_dtype<<<1, 256, 0, stream>>>((const u16*)X, dflag);

  gemm_any<<<gBig, 256, 0, stream>>>(X, Wq, proj, nullptr, 2048, 4096, 2048,
                                     EPI_F32, nullptr, nullptr, 2, 2, dflag);
  conv_silu_norm<<<gNH, 128, 0, stream>>>(proj, cq, qb, 2, dflag);
  gemm_any<<<gBig, 256, 0, stream>>>(X, Wk, proj, nullptr, 2048, 4096, 2048,
                                     EPI_F32, nullptr, nullptr, 2, 2, dflag);
  conv_silu_norm<<<gNH, 128, 0, stream>>>(proj, ck, kb, 1, dflag);
  gemm_any<<<gBig, 256, 0, stream>>>(X, Wv, proj, nullptr, 2048, 4096, 2048,
                                     EPI_F32, nullptr, nullptr, 2, 2, dflag);
  conv_silu_norm<<<gNH, 128, 0, stream>>>(proj, cv, vb, 0, dflag);

  gemm_any<<<gLow, 256, 0, stream>>>(X, Wfa, nullptr, flowb, 2048, 128, 2048,
                                     EPI_BF16, nullptr, nullptr, 2, 2, dflag);
  gemm_any<<<gLow, 256, 0, stream>>>(X, Wga, nullptr, glowb, 2048, 128, 2048,
                                     EPI_BF16, nullptr, nullptr, 2, 2, dflag);
  beta_kernel<<<2048, 64, 0, stream>>>(X, Wb, betab, dflag);

  gemm_any<<<gBig, 256, 0, stream>>>(flowb, Wfb, eg, nullptr, 2048, 4096, 128,
                                     EPI_EG, dtb, Alog, 1, 2, dflag);

  scan_kernel<<<256, 256, 0, stream>>>(qb, kb, vb, eg, betab, core);

  gemm_any<<<gBig, 256, 0, stream>>>(glowb, Wgb, nullptr, sgb, 2048, 4096, 128,
                                     EPI_SIG, nullptr, nullptr, 1, 2, dflag);
  rms_gate<<<gNH, 128, 0, stream>>>(core, sgb, onw, rmsb, dflag);

  gemm_any<<<gOut, 256, 0, stream>>>(rmsb, Wo, (float*)d_out, (u16*)d_out,
                                     2048, 2048, 4096, EPI_OUT,
                                     nullptr, nullptr, 1, 2, dflag);
}